// Round 1
// baseline (380.128 us; speedup 1.0000x reference)
//
#include <hip/hip_runtime.h>
#include <math.h>

#define C_DIM 256
#define HW 16384           // 128*128
#define HW4 4096           // HW / 4

// Kernel 1: fused global avg+max pool per (b,c) plane.
// grid = B*C = 4096 blocks, 256 threads. Each plane is 16384 contiguous floats.
__global__ __launch_bounds__(256) void pool_kernel(const float* __restrict__ x,
                                                   float* __restrict__ avg,
                                                   float* __restrict__ mx) {
    const int plane = blockIdx.x;  // b*C + c
    const float4* p = reinterpret_cast<const float4*>(x + (size_t)plane * HW);

    float s = 0.0f;
    float m = -INFINITY;
#pragma unroll
    for (int i = 0; i < HW4 / 256; ++i) {   // 16 float4 per thread
        float4 v = p[threadIdx.x + i * 256];
        s += (v.x + v.y) + (v.z + v.w);
        m = fmaxf(m, fmaxf(fmaxf(v.x, v.y), fmaxf(v.z, v.w)));
    }

    // wave-64 shuffle reduction
#pragma unroll
    for (int off = 32; off > 0; off >>= 1) {
        s += __shfl_down(s, off, 64);
        m = fmaxf(m, __shfl_down(m, off, 64));
    }

    __shared__ float ss[4];
    __shared__ float sm[4];
    const int lane = threadIdx.x & 63;
    const int wave = threadIdx.x >> 6;
    if (lane == 0) { ss[wave] = s; sm[wave] = m; }
    __syncthreads();
    if (threadIdx.x == 0) {
        float S = (ss[0] + ss[1]) + (ss[2] + ss[3]);
        float M = fmaxf(fmaxf(sm[0], sm[1]), fmaxf(sm[2], sm[3]));
        avg[plane] = S * (1.0f / (float)HW);
        mx[plane]  = M;
    }
}

// Kernel 2: per-batch shared MLP on both pooled vectors + sigmoid.
// grid = B = 16 blocks, 256 threads (one per output channel o).
// h = relu(w1 @ v); out = sigmoid(w2 @ h_avg + w2 @ h_max)
__global__ __launch_bounds__(256) void mlp_kernel(const float* __restrict__ w1,
                                                  const float* __restrict__ w2,
                                                  const float* __restrict__ avg,
                                                  const float* __restrict__ mx,
                                                  float* __restrict__ out) {
    const int b = blockIdx.x;
    const int o = threadIdx.x;

    __shared__ float sa[C_DIM];   // avg vector for this batch
    __shared__ float sx[C_DIM];   // max vector
    __shared__ float ha[C_DIM];   // relu(w1@avg)
    __shared__ float hx[C_DIM];   // relu(w1@max)

    sa[o] = avg[b * C_DIM + o];
    sx[o] = mx[b * C_DIM + o];
    __syncthreads();

    // layer 1: thread o = row o of w1
    {
        const float* w1r = w1 + (size_t)o * C_DIM;
        float da = 0.0f, dm = 0.0f;
#pragma unroll 4
        for (int c = 0; c < C_DIM; ++c) {
            const float w = w1r[c];
            da = fmaf(w, sa[c], da);
            dm = fmaf(w, sx[c], dm);
        }
        ha[o] = fmaxf(da, 0.0f);
        hx[o] = fmaxf(dm, 0.0f);
    }
    __syncthreads();

    // layer 2 + sigmoid
    {
        const float* w2r = w2 + (size_t)o * C_DIM;
        float oa = 0.0f, om = 0.0f;
#pragma unroll 4
        for (int c = 0; c < C_DIM; ++c) {
            const float w = w2r[c];
            oa = fmaf(w, ha[c], oa);
            om = fmaf(w, hx[c], om);
        }
        const float v = oa + om;
        out[b * C_DIM + o] = 1.0f / (1.0f + expf(-v));
    }
}

extern "C" void kernel_launch(void* const* d_in, const int* in_sizes, int n_in,
                              void* d_out, int out_size, void* d_ws, size_t ws_size,
                              hipStream_t stream) {
    const float* x  = (const float*)d_in[0];   // [16,256,128,128]
    const float* w1 = (const float*)d_in[1];   // [256,256]
    const float* w2 = (const float*)d_in[2];   // [256,256]
    float* out = (float*)d_out;                // [16,256] (== [16,256,1,1] flat)

    float* avg = (float*)d_ws;                 // 4096 floats
    float* mx  = avg + 16 * C_DIM;             // 4096 floats

    pool_kernel<<<16 * C_DIM, 256, 0, stream>>>(x, avg, mx);
    mlp_kernel<<<16, 256, 0, stream>>>(w1, w2, avg, mx, out);
}

// Round 2
// 355.161 us; speedup vs baseline: 1.0703x; 1.0703x over previous
//
#include <hip/hip_runtime.h>
#include <math.h>

#define C_DIM 256
#define HW 16384           // 128*128
#define HW4 4096           // HW / 4

typedef float vfloat4 __attribute__((ext_vector_type(4)));

// Kernel 1: fused global avg+max pool per (b,c) plane.
// grid = B*C = 4096 blocks, 256 threads. Each plane is 16384 contiguous floats.
// Streaming read of 256 MB with zero reuse -> nontemporal loads (nt) so we
// don't churn L2 for data we never touch again.
__global__ __launch_bounds__(256) void pool_kernel(const float* __restrict__ x,
                                                   float* __restrict__ avg,
                                                   float* __restrict__ mx) {
    const int plane = blockIdx.x;  // b*C + c
    const vfloat4* p = reinterpret_cast<const vfloat4*>(x + (size_t)plane * HW);

    float s = 0.0f;
    float m = -INFINITY;
#pragma unroll
    for (int i = 0; i < HW4 / 256; ++i) {   // 16 float4 per thread, independent
        vfloat4 v = __builtin_nontemporal_load(&p[threadIdx.x + i * 256]);
        s += (v.x + v.y) + (v.z + v.w);
        m = fmaxf(m, fmaxf(fmaxf(v.x, v.y), fmaxf(v.z, v.w)));
    }

    // wave-64 shuffle reduction
#pragma unroll
    for (int off = 32; off > 0; off >>= 1) {
        s += __shfl_down(s, off, 64);
        m = fmaxf(m, __shfl_down(m, off, 64));
    }

    __shared__ float ss[4];
    __shared__ float sm[4];
    const int lane = threadIdx.x & 63;
    const int wave = threadIdx.x >> 6;
    if (lane == 0) { ss[wave] = s; sm[wave] = m; }
    __syncthreads();
    if (threadIdx.x == 0) {
        float S = (ss[0] + ss[1]) + (ss[2] + ss[3]);
        float M = fmaxf(fmaxf(sm[0], sm[1]), fmaxf(sm[2], sm[3]));
        avg[plane] = S * (1.0f / (float)HW);
        mx[plane]  = M;
    }
}

// Kernel 2: per-batch shared MLP on both pooled vectors + sigmoid.
// grid = B = 16 blocks, 256 threads (one per output channel o).
// h = relu(w1 @ v); out = sigmoid(w2 @ h_avg + w2 @ h_max)
// Weight rows loaded as float4 bursts (64 VMEM insts/row instead of 256).
__global__ __launch_bounds__(256) void mlp_kernel(const float* __restrict__ w1,
                                                  const float* __restrict__ w2,
                                                  const float* __restrict__ avg,
                                                  const float* __restrict__ mx,
                                                  float* __restrict__ out) {
    const int b = blockIdx.x;
    const int o = threadIdx.x;

    __shared__ float sa[C_DIM];   // avg vector for this batch
    __shared__ float sx[C_DIM];   // max vector
    __shared__ float ha[C_DIM];   // relu(w1@avg)
    __shared__ float hx[C_DIM];   // relu(w1@max)

    sa[o] = avg[b * C_DIM + o];
    sx[o] = mx[b * C_DIM + o];
    __syncthreads();

    // layer 1: thread o = row o of w1
    {
        const vfloat4* w1r = reinterpret_cast<const vfloat4*>(w1 + (size_t)o * C_DIM);
        float da = 0.0f, dm = 0.0f;
#pragma unroll 4
        for (int c4 = 0; c4 < C_DIM / 4; ++c4) {
            const vfloat4 w = w1r[c4];
            const int c = c4 * 4;
            da = fmaf(w.x, sa[c + 0], da);  dm = fmaf(w.x, sx[c + 0], dm);
            da = fmaf(w.y, sa[c + 1], da);  dm = fmaf(w.y, sx[c + 1], dm);
            da = fmaf(w.z, sa[c + 2], da);  dm = fmaf(w.z, sx[c + 2], dm);
            da = fmaf(w.w, sa[c + 3], da);  dm = fmaf(w.w, sx[c + 3], dm);
        }
        ha[o] = fmaxf(da, 0.0f);
        hx[o] = fmaxf(dm, 0.0f);
    }
    __syncthreads();

    // layer 2 + sigmoid
    {
        const vfloat4* w2r = reinterpret_cast<const vfloat4*>(w2 + (size_t)o * C_DIM);
        float oa = 0.0f, om = 0.0f;
#pragma unroll 4
        for (int c4 = 0; c4 < C_DIM / 4; ++c4) {
            const vfloat4 w = w2r[c4];
            const int c = c4 * 4;
            oa = fmaf(w.x, ha[c + 0], oa);  om = fmaf(w.x, hx[c + 0], om);
            oa = fmaf(w.y, ha[c + 1], oa);  om = fmaf(w.y, hx[c + 1], om);
            oa = fmaf(w.z, ha[c + 2], oa);  om = fmaf(w.z, hx[c + 2], om);
            oa = fmaf(w.w, ha[c + 3], oa);  om = fmaf(w.w, hx[c + 3], om);
        }
        const float v = oa + om;
        out[b * C_DIM + o] = 1.0f / (1.0f + expf(-v));
    }
}

extern "C" void kernel_launch(void* const* d_in, const int* in_sizes, int n_in,
                              void* d_out, int out_size, void* d_ws, size_t ws_size,
                              hipStream_t stream) {
    const float* x  = (const float*)d_in[0];   // [16,256,128,128]
    const float* w1 = (const float*)d_in[1];   // [256,256]
    const float* w2 = (const float*)d_in[2];   // [256,256]
    float* out = (float*)d_out;                // [16,256] (== [16,256,1,1] flat)

    float* avg = (float*)d_ws;                 // 4096 floats
    float* mx  = avg + 16 * C_DIM;             // 4096 floats

    pool_kernel<<<16 * C_DIM, 256, 0, stream>>>(x, avg, mx);
    mlp_kernel<<<16, 256, 0, stream>>>(w1, w2, avg, mx, out);
}